// Round 5
// baseline (282.110 us; speedup 1.0000x reference)
//
#include <hip/hip_runtime.h>

// LSTM B=4096 T=512 IN=14 H=28 OUT=2, fp32 in/out.
// 2 blocks/CU (grid 512, MB=8, 256thr = 4 waves) with INDEPENDENT barriers so
// one block's barrier/ds_read stall hides under the other's compute (round-4's
// 1-block design drained the whole CU at every __syncthreads: 540cy/step stall).
// Full-lane gate math despite MB=8 via column duplication:
//   A = weights, tile s in {0,1}: row R -> (gate R&3, unit 8w + 2*(R>>2) + s).
//   B = data, cols 0..15 = batches 0..7 duplicated (m&7) -> broadcast reads.
//   Lane (q,m): tile-s C regs j = gate-j preact of unit 8w+2q+s, batch m&7.
//   Lane m<8 gates tile 0 (even unit u0=8w+2q), lane m>=8 gates tile 1 (u0+1),
//   batch m&7: the duplication IS the distribution - one gate4 per lane,
//   4 cndmasks, no cross-lane ops.
// h-write: ds_swizzle(xor 8) fetches the partner (odd-unit) h, cvt_pk packs the
// bf16 pair, lanes m<8 do one b32 write at [b][u0] - banks (b*20+4w+q)%32 all
// distinct -> conflict-free.
// x-projection off critical path: accx_{t+1} = bias + W_ih*x_{t+1} via 2 MFMAs
// issued during step t. Step chain: read bh -> 2 h-MFMA (C=accx) -> gate4 ->
// swizzle+pack+write -> ONE barrier. h double-buffered by step parity.
// x staged per 16-step chunk (double-buffered LDS); next chunk's global loads
// held in 7 VGPRs across the chunk.

#define T_STEPS 512
#define BATCH   4096
#define IN_F    14
#define HID     28
#define OUT_N   2
#define MB      8                  // batch per block
#define TC      16                 // timesteps per x chunk
#define NCHUNK  (T_STEPS / TC)     // 32
#define HPITCH  40                 // shorts per B-row (80 B, 16B-aligned)
#define NTHR    256
#define XREGS   ((MB * TC * IN_F) / NTHR)   // 7 fp32 per thread per chunk

typedef __attribute__((ext_vector_type(8))) short  short8;
typedef __attribute__((ext_vector_type(4))) float  float4v;

#define L1 1.4426950408889634f
#define L2 2.8853900817779268f

__device__ __forceinline__ unsigned short f2bf(float f) {
    union { float f; unsigned int u; } v; v.f = f;
    unsigned int r = (v.u + 0x7FFFu + ((v.u >> 16) & 1u)) >> 16;  // RNE
    return (unsigned short)r;
}

__device__ __forceinline__ int cvtpk_bf16(float lo, float hi) {
    int r;
    asm("v_cvt_pk_bf16_f32 %0, %1, %2" : "=v"(r) : "v"(lo), "v"(hi));
    return r;
}

__device__ __forceinline__ void gate4(const float4v pr, float& c, float& hf) {
    // pr[0]=i, pr[1]=f, pr[2]=g, pr[3]=o raw preacts
    float ei = __builtin_amdgcn_exp2f(pr[0] * (-L1));
    float ef = __builtin_amdgcn_exp2f(pr[1] * (-L1));
    float eg = __builtin_amdgcn_exp2f(pr[2] * (-L2));
    float eo = __builtin_amdgcn_exp2f(pr[3] * (-L1));
    float av = 1.0f + ei, bv = 1.0f + ef, dv = 1.0f + eg, vv = 1.0f + eo;
    float pd  = av * dv;
    float pqv = pd * bv;
    float rv  = __builtin_amdgcn_rcpf(pqv);
    float sfv = pd * rv;                       // sigma(f)
    float igv = (1.0f - eg) * bv * rv;         // sigma(i)*tanh(g)
    c = fmaf(sfv, c, igv);
    float ec = __builtin_amdgcn_exp2f(c * (-L2));
    float wv = 1.0f + ec;
    float r2 = __builtin_amdgcn_rcpf(vv * wv);
    hf = (1.0f - ec) * r2;                     // sigma(o)*tanh(c)
}

__global__ __launch_bounds__(256, 2)
void lstm_d2(const float* __restrict__ x,
             const float* __restrict__ W_ih,
             const float* __restrict__ W_hh,
             const float* __restrict__ b_ih,
             const float* __restrict__ b_hh,
             const float* __restrict__ W_out,
             const float* __restrict__ b_out,
             float* __restrict__ out) {
    __shared__ __align__(16) short h_a[2][MB][HPITCH];         // bf16 h (units 0..27; 28..39 = 0)
    __shared__ __align__(16) short x_a[2][TC][MB][HPITCH];     // bf16 x (feats 0..13; 14..39 = 0)
    __shared__ float hfin[MB][HID];                            // f32 h for epilogue

    const int tid = threadIdx.x;
    const int w   = tid >> 6;        // wave: units [8w, 8w+8) across 2 tiles
    const int l   = tid & 63;
    const int q   = l >> 4;
    const int m   = l & 15;
    const int bb8 = m & 7;           // batch (cols 8..15 duplicate 0..7)
    const int sel = m >> 3;          // which tile this lane gates
    const int u0  = 8 * w + 2 * q;   // even unit of this lane's pair
    const int u   = u0 + sel;        // unit this lane gates
    const int b0  = blockIdx.x * MB;

    // ---- A-frag weights (bf16) + bias as C-init ----
    // A-frag tile s, lane (q,m): row m -> (gate m&3, unit 8w + 2*(m>>2) + s).
    short8  Ah[2], Ax[2];
    float4v bias[2];
    #pragma unroll
    for (int s = 0; s < 2; ++s) {
        const int ua = 8 * w + 2 * (m >> 2) + s;     // A-row unit
        const bool vr = (ua < HID);
        const int wrow = (m & 3) * HID + (vr ? ua : 0);
        short8 vh = {0,0,0,0,0,0,0,0}, vx = {0,0,0,0,0,0,0,0};
        #pragma unroll
        for (int j = 0; j < 8; ++j) {
            const int k = 8 * q + j;
            float wh = (vr && k < HID)  ? W_hh[wrow * HID + k]  : 0.0f;
            float wx = (vr && k < IN_F) ? W_ih[wrow * IN_F + k] : 0.0f;
            vh[j] = (short)f2bf(wh);
            vx[j] = (short)f2bf(wx);
        }
        Ah[s] = vh;
        Ax[s] = vx;
        // C regs j of tile s = gate j of unit us = 8w+2q+s (indep of j)
        const int us = u0 + s;
        float4v bv;
        #pragma unroll
        for (int j = 0; j < 4; ++j)
            bv[j] = (us < HID) ? (b_ih[j * HID + us] + b_hh[j * HID + us]) : 0.0f;
        bias[s] = bv;
    }

    // ---- zero LDS (h0 = 0; pads stay 0 forever) ----
    for (int k = tid; k < 2 * MB * HPITCH; k += NTHR) ((short*)h_a)[k] = 0;
    for (int k = tid; k < 2 * TC * MB * HPITCH; k += NTHR) ((short*)x_a)[k] = 0;

    // ---- prefetch chunk 0 into registers ----
    const float* xbase = x + (long)b0 * T_STEPS * IN_F;
    float xr[XREGS];
    #pragma unroll
    for (int k = 0; k < XREGS; ++k) {
        const int u2 = tid + NTHR * k;
        const int bb = u2 / (TC * IN_F);
        const int r  = u2 - bb * (TC * IN_F);
        xr[k] = xbase[(long)bb * T_STEPS * IN_F + r];
    }
    __syncthreads();   // zero-init visible

    const bool wact = (m < 8) && (u0 + 1 < HID);   // packed-write owner
    float c = 0.0f, hf = 0.0f;
    float4v accx0, accx1;

    for (int ch = 0; ch < NCHUNK; ++ch) {
        const int buf = ch & 1;
        // convert held registers -> bf16 B-layout for this chunk
        #pragma unroll
        for (int k = 0; k < XREGS; ++k) {
            const int u2 = tid + NTHR * k;
            const int bb = u2 / (TC * IN_F);
            const int r  = u2 - bb * (TC * IN_F);
            const int t  = r / IN_F;
            const int f  = r - t * IN_F;
            x_a[buf][t][bb][f] = (short)f2bf(xr[k]);
        }
        // issue next chunk's global loads (consumed TC steps later)
        if (ch + 1 < NCHUNK) {
            #pragma unroll
            for (int k = 0; k < XREGS; ++k) {
                const int u2 = tid + NTHR * k;
                const int bb = u2 / (TC * IN_F);
                const int r  = u2 - bb * (TC * IN_F);
                xr[k] = xbase[(long)bb * T_STEPS * IN_F + (ch + 1) * TC * IN_F + r];
            }
        }
        __syncthreads();   // x_a[buf] visible

        // accx for step 0 of this chunk
        {
            short8 bx0 = *(const short8*)&x_a[buf][0][bb8][8 * q];
            accx0 = __builtin_amdgcn_mfma_f32_16x16x32_bf16(Ax[0], bx0, bias[0], 0, 0, 0);
            accx1 = __builtin_amdgcn_mfma_f32_16x16x32_bf16(Ax[1], bx0, bias[1], 0, 0, 0);
        }

        #pragma unroll
        for (int tt = 0; tt < TC; ++tt) {
            const int rd = tt & 1;               // chunk has even step count ->
            const int wr = rd ^ 1;               // rd=0 at every chunk top
            short8 bh = *(const short8*)&h_a[rd][bb8][8 * q];
            float4v a0 = __builtin_amdgcn_mfma_f32_16x16x32_bf16(Ah[0], bh, accx0, 0, 0, 0);
            float4v a1 = __builtin_amdgcn_mfma_f32_16x16x32_bf16(Ah[1], bh, accx1, 0, 0, 0);
            // next step's x part — independent, fills MFMA pipe during gate math
            if (tt + 1 < TC) {
                short8 bxn = *(const short8*)&x_a[buf][tt + 1][bb8][8 * q];
                accx0 = __builtin_amdgcn_mfma_f32_16x16x32_bf16(Ax[0], bxn, bias[0], 0, 0, 0);
                accx1 = __builtin_amdgcn_mfma_f32_16x16x32_bf16(Ax[1], bxn, bias[1], 0, 0, 0);
            }
            // lane picks its tile: m<8 -> tile0 (unit u0), m>=8 -> tile1 (u0+1)
            float4v acc;
            #pragma unroll
            for (int j = 0; j < 4; ++j) acc[j] = sel ? a1[j] : a0[j];
            gate4(acc, c, hf);
            // pack (even,odd) unit pair: partner h from lane^8, one b32 write
            int hpart = __builtin_amdgcn_ds_swizzle(__builtin_bit_cast(int, hf), 0x201F);
            if (wact)
                *(int*)&h_a[wr][m][u0] = cvtpk_bf16(hf, __builtin_bit_cast(float, hpart));
            __syncthreads();   // h_{t+1} visible
        }
    }

    // ---- epilogue: out[b][o] = h_T[b] . W_out[o] + b_out[o] ----
    if (u < HID) hfin[bb8][u] = hf;
    __syncthreads();
    if (tid < MB * OUT_N) {
        const int o  = tid & 1;
        const int bb = tid >> 1;
        float s = b_out[o];
        #pragma unroll
        for (int k = 0; k < HID; ++k)
            s = fmaf(hfin[bb][k], W_out[o * HID + k], s);
        out[(b0 + bb) * OUT_N + o] = s;
    }
}

extern "C" void kernel_launch(void* const* d_in, const int* in_sizes, int n_in,
                              void* d_out, int out_size, void* d_ws, size_t ws_size,
                              hipStream_t stream) {
    const float* x     = (const float*)d_in[0];
    const float* W_ih  = (const float*)d_in[1];
    const float* W_hh  = (const float*)d_in[2];
    const float* b_ih  = (const float*)d_in[3];
    const float* b_hh  = (const float*)d_in[4];
    const float* W_out = (const float*)d_in[5];
    const float* b_out = (const float*)d_in[6];
    float* out = (float*)d_out;

    lstm_d2<<<BATCH / MB, NTHR, 0, stream>>>(
        x, W_ih, W_hh, b_ih, b_hh, W_out, b_out, out);
}